// Round 11
// baseline (265.170 us; speedup 1.0000x reference)
//
#include <hip/hip_runtime.h>
#include <hip/hip_bf16.h>
#include <hip/hip_fp16.h>

// GCN 2-layer: out = Ahat * relu(Ahat*(X W1)+b1) * W2 + b2
// Round 11: scalarized aggregate. The whole wave processes one dst row, so
// row_ptr/csr_src loads, clamping, and the src-row base address are wave-
// uniform -> forced into the SALU/s_load pipe via readfirstlane. Per-edge
// vector work is just cvt+add; VMEM is one 2B/lane row-gather per edge.
// F=32 also one row/wave (upper 32 lanes mirror, same cache line).
// Rest identical to round 10 (tail-free 8-deep batches, zero pad row at n,
// atomic-free bucketed CSR build, fp16 gather tables).

#define N_FEAT_IN 64
#define B2SHIFT 9        // 512 dst nodes per coarse bucket
#define CHUNK 4096       // edges per block in pass A/B

struct alignas(8) half4 { __half2 lo, hi; };

// ---- pass A: per-chunk bucket histogram (LDS, no global atomics) ----
__global__ __launch_bounds__(256) void passA_hist(const int* __restrict__ dst,
                                                  int* __restrict__ H, int E) {
    __shared__ int h[256];
    h[threadIdx.x] = 0;
    __syncthreads();
    int base = blockIdx.x * CHUNK;
    int end = min(base + CHUNK, E);
    for (int i = base + threadIdx.x; i < end; i += 256)
        atomicAdd(&h[dst[i] >> B2SHIFT], 1);
    __syncthreads();
    H[blockIdx.x * 256 + threadIdx.x] = h[threadIdx.x];
}

// ---- col_scan_a: one block per column; exclusive scan over NR rows ----
__global__ __launch_bounds__(512) void col_scan_a(int* __restrict__ H,
                                                  int* __restrict__ ctot, int NR) {
    __shared__ int s[512];
    int b = blockIdx.x;
    int t = threadIdx.x;
    int v = (t < NR) ? H[t * 256 + b] : 0;
    s[t] = v;
    __syncthreads();
    for (int off = 1; off < 512; off <<= 1) {
        int a = (t >= off) ? s[t - off] : 0;
        __syncthreads();
        s[t] += a;
        __syncthreads();
    }
    if (t < NR) H[t * 256 + b] = s[t] - v;
    if (t == 511) ctot[b] = s[511];
}

// ---- col_scan_b: scan column totals -> per-bucket bases; row_ptr[n]=E ----
__global__ __launch_bounds__(256) void col_scan_b(const int* __restrict__ ctot,
                                                  int* __restrict__ cbase,
                                                  int* __restrict__ bbase,
                                                  int* __restrict__ row_ptr,
                                                  int NB, int n, int E) {
    __shared__ int s[256];
    int t = threadIdx.x;
    int v = ctot[t];
    s[t] = v;
    __syncthreads();
    for (int off = 1; off < 256; off <<= 1) {
        int a = (t >= off) ? s[t - off] : 0;
        __syncthreads();
        s[t] += a;
        __syncthreads();
    }
    int e = s[t] - v;
    cbase[t] = e;
    if (t < NB) bbase[t] = e;
    if (t == 0) { bbase[NB] = E; row_ptr[n] = E; }
}

// ---- pass B: place packed edges into private per-chunk runs ----
__global__ __launch_bounds__(256) void passB_place(const int* __restrict__ src,
                                                   const int* __restrict__ dst,
                                                   const int* __restrict__ H,
                                                   const int* __restrict__ cbase,
                                                   unsigned* __restrict__ bedges, int E) {
    __shared__ int cur[256];
    cur[threadIdx.x] = H[blockIdx.x * 256 + threadIdx.x] + cbase[threadIdx.x];
    __syncthreads();
    int base = blockIdx.x * CHUNK;
    int end = min(base + CHUNK, E);
    for (int i = base + threadIdx.x; i < end; i += 256) {
        int d = dst[i];
        int p = atomicAdd(&cur[d >> B2SHIFT], 1);  // LDS atomic
        bedges[p] = ((unsigned)src[i] << B2SHIFT) | (unsigned)(d & 511);
    }
}

// ---- merged: per-bucket hist -> local scan -> row_ptr/dinv -> CSR scatter ----
__global__ __launch_bounds__(256) void bucket_csr(const int* __restrict__ bbase,
                                                  const unsigned* __restrict__ bedges,
                                                  int* __restrict__ row_ptr,
                                                  float* __restrict__ dinv,
                                                  int* __restrict__ csr_src, int n) {
    __shared__ int lh[512];
    __shared__ int cur[512];
    int t = threadIdx.x;
    lh[t] = 0;
    lh[t + 256] = 0;
    __syncthreads();
    int b = blockIdx.x;
    int beg = bbase[b], end = bbase[b + 1];
    for (int i = beg + t; i < end; i += 256)
        atomicAdd(&lh[bedges[i] & 511], 1);
    __syncthreads();
    int c0 = lh[t], c1 = lh[t + 256];
    for (int off = 1; off < 512; off <<= 1) {
        int a0 = (t >= off) ? lh[t - off] : 0;
        int a1 = (t + 256 >= off) ? lh[t + 256 - off] : 0;
        __syncthreads();
        lh[t] += a0;
        lh[t + 256] += a1;
        __syncthreads();
    }
#pragma unroll
    for (int k = 0; k < 2; ++k) {
        int local = t + k * 256;
        int d = (b << B2SHIFT) + local;
        int c = (k == 0) ? c0 : c1;
        int excl = beg + lh[local] - c;
        cur[local] = excl;
        if (d < n) {
            row_ptr[d] = excl;
            dinv[d] = rsqrtf((float)c + 1.0f);
        }
    }
    __syncthreads();
    for (int i = beg + t; i < end; i += 256) {
        unsigned v = bedges[i];
        int p = atomicAdd(&cur[v & 511], 1);  // LDS atomic
        csr_src[p] = (int)(v >> B2SHIFT);
    }
}

// ---- GEMM: outh[n,FO] = half( dinv[row] * (preop(A[n,64]) * W[64,FO]) ) ----
// Also zeroes the pad row at index n (block 0).
template <int FO, bool RELU_BIAS>
__global__ __launch_bounds__(256) void gemm_rows(const float* __restrict__ A,
                                                 const float* __restrict__ W,
                                                 const float* __restrict__ bias,
                                                 const float* __restrict__ dinv,
                                                 __half* __restrict__ outh, int n) {
    constexpr int K = 64;
    constexpr int CPT = FO / 4;
    __shared__ float As[64][K + 4];
    __shared__ float Ws[K][FO];

    const int t = threadIdx.x;
    const int r0 = blockIdx.x * 64;

    if (blockIdx.x == 0 && t < FO)  // zero pad row n
        outh[(size_t)n * FO + t] = __float2half(0.f);

    constexpr int W4 = K * FO / 4;
    for (int i = t; i < W4; i += 256) {
        int k = i / (FO / 4);
        int c4 = (i % (FO / 4)) * 4;
        *(float4*)&Ws[k][c4] = *(const float4*)&W[k * FO + c4];
    }
    for (int i = t; i < 1024; i += 256) {
        int row = i / 16;
        int c4 = (i % 16) * 4;
        int g = r0 + row;
        float4 v = make_float4(0.f, 0.f, 0.f, 0.f);
        if (g < n) {
            v = *(const float4*)&A[(size_t)g * K + c4];
            if (RELU_BIAS) {
                v.x = fmaxf(v.x + bias[c4 + 0], 0.f);
                v.y = fmaxf(v.y + bias[c4 + 1], 0.f);
                v.z = fmaxf(v.z + bias[c4 + 2], 0.f);
                v.w = fmaxf(v.w + bias[c4 + 3], 0.f);
            }
        }
        *(float4*)&As[row][c4] = v;
    }
    __syncthreads();

    const int row = t >> 2;
    const int c0 = (t & 3) * CPT;
    float acc[CPT];
#pragma unroll
    for (int j = 0; j < CPT; ++j) acc[j] = 0.f;

#pragma unroll
    for (int k = 0; k < K; ++k) {
        float xv = As[row][k];
#pragma unroll
        for (int j = 0; j < CPT; ++j) acc[j] = fmaf(xv, Ws[k][c0 + j], acc[j]);
    }

    int g = r0 + row;
    if (g < n) {
        float sc = dinv[g];
#pragma unroll
        for (int j4 = 0; j4 < CPT; j4 += 4) {
            half4 h;
            h.lo = __floats2half2_rn(acc[j4] * sc, acc[j4 + 1] * sc);
            h.hi = __floats2half2_rn(acc[j4 + 2] * sc, acc[j4 + 3] * sc);
            *(half4*)&outh[(size_t)g * FO + c0 + j4] = h;
        }
    }
}

// ---- scalarized pull aggregation ----
// One wave per dst row (F=64: lane=feature; F=32: lanes 32-63 mirror 0-31).
// d forced wave-uniform -> row_ptr/csr_src loads go to s_load; clamp in SALU;
// xs loads are SGPR-base + lane offset; per-edge VALU = cvt+add only.
template <int F, bool ADD_BIAS>
__global__ __launch_bounds__(256) void aggregate(const int* __restrict__ row_ptr,
                                                 const int* __restrict__ csr_src,
                                                 const float* __restrict__ dinv,
                                                 const __half* __restrict__ xs,
                                                 const float* __restrict__ bias,
                                                 float* __restrict__ out, int n) {
    int d = __builtin_amdgcn_readfirstlane(blockIdx.x * 4 + (threadIdx.x >> 6));
    if (d >= n) return;
    int lane = threadIdx.x & 63;
    int f = lane & (F - 1);

    int beg = row_ptr[d];       // uniform -> s_load
    int end = row_ptr[d + 1];
    float acc = __half2float(xs[(size_t)d * F + f]);  // self-loop term

    for (int jb = beg; jb < end; jb += 8) {
        int idx[8];
#pragma unroll
        for (int k = 0; k < 8; ++k) {
            int j = jb + k;
            int s = csr_src[min(j, end - 1)];          // uniform -> s_load
            idx[k] = __builtin_amdgcn_readfirstlane((j < end) ? s : n);
        }
        float v[8];
#pragma unroll
        for (int k = 0; k < 8; ++k)
            v[k] = __half2float(xs[(size_t)idx[k] * F + f]);  // SGPR base + lane off
        acc += ((v[0] + v[1]) + (v[2] + v[3])) + ((v[4] + v[5]) + (v[6] + v[7]));
    }

    float r = dinv[d] * acc;
    if (ADD_BIAS) r += bias[f];
    if (F == 64 || lane < F)
        out[(size_t)d * F + f] = r;
}

extern "C" void kernel_launch(void* const* d_in, const int* in_sizes, int n_in,
                              void* d_out, int out_size, void* d_ws, size_t ws_size,
                              hipStream_t stream) {
    const float* x  = (const float*)d_in[0];   // [n, 64]
    const int*   ei = (const int*)d_in[1];     // [2, E]
    const float* W1 = (const float*)d_in[2];   // [64, 64]
    const float* b1 = (const float*)d_in[3];   // [64]
    const float* W2 = (const float*)d_in[4];   // [64, 32]
    const float* b2 = (const float*)d_in[5];   // [32]
    float* out = (float*)d_out;                // [n, 32]

    const int n = in_sizes[0] / N_FEAT_IN;     // 100000
    const int E = in_sizes[1] / 2;             // 1600000
    const int* srcI = ei;
    const int* dstI = ei + E;

    const int NB = (n + 511) >> B2SHIFT;       // 196 coarse buckets
    const int NR = (E + CHUNK - 1) / CHUNK;    // 391 chunks

    // workspace layout (256B aligned)
    char* ws = (char*)d_ws;
    size_t off = 0;
    auto alloc = [&](size_t bytes) {
        void* p = ws + off;
        off += (bytes + 255) & ~(size_t)255;
        return p;
    };
    float*    dinv    = (float*)alloc((size_t)n * 4);
    int*      row_ptr = (int*)alloc((size_t)(n + 1) * 4);
    int*      bbase   = (int*)alloc((size_t)(NB + 1) * 4);
    int*      ctot    = (int*)alloc((size_t)256 * 4);
    int*      cbase   = (int*)alloc((size_t)256 * 4);
    int*      H       = (int*)alloc((size_t)NR * 256 * 4);   // ~400KB
    unsigned* bedges  = (unsigned*)alloc((size_t)E * 4);
    int*      csr_src = (int*)alloc((size_t)E * 4);
    __half*   xs      = (__half*)alloc((size_t)(n + 1) * 64 * 2); // +1 pad row
    float*    agg1    = (float*)alloc((size_t)n * 64 * 4);

    // 1) atomic-free bucket sort by dst>>9
    passA_hist<<<NR, 256, 0, stream>>>(dstI, H, E);
    col_scan_a<<<256, 512, 0, stream>>>(H, ctot, NR);
    col_scan_b<<<1, 256, 0, stream>>>(ctot, cbase, bbase, row_ptr, NB, n, E);
    passB_place<<<NR, 256, 0, stream>>>(srcI, dstI, H, cbase, bedges, E);

    // 2) merged: row_ptr + dinv + CSR scatter
    bucket_csr<<<NB, 256, 0, stream>>>(bbase, bedges, row_ptr, dinv, csr_src, n);

    // 3) layer 1: xs = half(dinv .* (X W1)); agg1 = dinv .* (gather + self)
    gemm_rows<64, false><<<(n + 63) / 64, 256, 0, stream>>>(x, W1, nullptr, dinv, xs, n);
    aggregate<64, false><<<(n + 3) / 4, 256, 0, stream>>>(row_ptr, csr_src, dinv, xs, nullptr, agg1, n);

    // 4) layer 2: xs2 = half(dinv .* (relu(agg1+b1) W2)); out = ... + b2
    gemm_rows<32, true><<<(n + 63) / 64, 256, 0, stream>>>(agg1, W2, b1, dinv, xs, n);
    aggregate<32, true><<<(n + 3) / 4, 256, 0, stream>>>(row_ptr, csr_src, dinv, xs, b2, out, n);
}

// Round 12
// 234.293 us; speedup vs baseline: 1.1318x; 1.1318x over previous
//
#include <hip/hip_runtime.h>
#include <hip/hip_bf16.h>
#include <hip/hip_fp16.h>

// GCN 2-layer: out = Ahat * relu(Ahat*(X W1)+b1) * W2 + b2
// Round 12:
//  - agg64 FUSED with layer-2 transform: after the wave reduces row d, lanes
//    hold the 64-feature row -> relu(+b1), LDS wave-broadcast, xW2 (split-k
//    over half-waves + shfl_xor(32)), xdinv, write fp16 xs2. gemm32 kernel
//    and the 50MB agg1 round-trip deleted.
//  - agg32 reverted to R10 2-rows/wave clamped form (R11 mirroring regressed).
//  - build kernels at 1024 threads/block (passA/passB/bucket_csr were 1-1.5
//    blocks/CU with serial loops -> latency-exposed; 16 waves/block hides it).

#define N_FEAT_IN 64
#define B2SHIFT 9        // 512 dst nodes per coarse bucket
#define CHUNK 4096       // edges per block in pass A/B

struct alignas(8) half4 { __half2 lo, hi; };

// ---- pass A: per-chunk bucket histogram (LDS, no global atomics) ----
__global__ __launch_bounds__(1024) void passA_hist(const int* __restrict__ dst,
                                                   int* __restrict__ H, int E) {
    __shared__ int h[256];
    int t = threadIdx.x;
    if (t < 256) h[t] = 0;
    __syncthreads();
    int base = blockIdx.x * CHUNK;
    int end = min(base + CHUNK, E);
    for (int i = base + t; i < end; i += 1024)
        atomicAdd(&h[dst[i] >> B2SHIFT], 1);
    __syncthreads();
    if (t < 256) H[blockIdx.x * 256 + t] = h[t];
}

// ---- col_scan_a: one block per column; exclusive scan over NR rows ----
__global__ __launch_bounds__(512) void col_scan_a(int* __restrict__ H,
                                                  int* __restrict__ ctot, int NR) {
    __shared__ int s[512];
    int b = blockIdx.x;
    int t = threadIdx.x;
    int v = (t < NR) ? H[t * 256 + b] : 0;
    s[t] = v;
    __syncthreads();
    for (int off = 1; off < 512; off <<= 1) {
        int a = (t >= off) ? s[t - off] : 0;
        __syncthreads();
        s[t] += a;
        __syncthreads();
    }
    if (t < NR) H[t * 256 + b] = s[t] - v;
    if (t == 511) ctot[b] = s[511];
}

// ---- col_scan_b: scan column totals -> per-bucket bases; row_ptr[n]=E ----
__global__ __launch_bounds__(256) void col_scan_b(const int* __restrict__ ctot,
                                                  int* __restrict__ cbase,
                                                  int* __restrict__ bbase,
                                                  int* __restrict__ row_ptr,
                                                  int NB, int n, int E) {
    __shared__ int s[256];
    int t = threadIdx.x;
    int v = ctot[t];
    s[t] = v;
    __syncthreads();
    for (int off = 1; off < 256; off <<= 1) {
        int a = (t >= off) ? s[t - off] : 0;
        __syncthreads();
        s[t] += a;
        __syncthreads();
    }
    int e = s[t] - v;
    cbase[t] = e;
    if (t < NB) bbase[t] = e;
    if (t == 0) { bbase[NB] = E; row_ptr[n] = E; }
}

// ---- pass B: place packed edges into private per-chunk runs ----
__global__ __launch_bounds__(1024) void passB_place(const int* __restrict__ src,
                                                    const int* __restrict__ dst,
                                                    const int* __restrict__ H,
                                                    const int* __restrict__ cbase,
                                                    unsigned* __restrict__ bedges, int E) {
    __shared__ int cur[256];
    int t = threadIdx.x;
    if (t < 256) cur[t] = H[blockIdx.x * 256 + t] + cbase[t];
    __syncthreads();
    int base = blockIdx.x * CHUNK;
    int end = min(base + CHUNK, E);
    for (int i = base + t; i < end; i += 1024) {
        int d = dst[i];
        int p = atomicAdd(&cur[d >> B2SHIFT], 1);  // LDS atomic
        bedges[p] = ((unsigned)src[i] << B2SHIFT) | (unsigned)(d & 511);
    }
}

// ---- merged: per-bucket hist -> local scan -> row_ptr/dinv -> CSR scatter ----
__global__ __launch_bounds__(1024) void bucket_csr(const int* __restrict__ bbase,
                                                   const unsigned* __restrict__ bedges,
                                                   int* __restrict__ row_ptr,
                                                   float* __restrict__ dinv,
                                                   int* __restrict__ csr_src, int n) {
    __shared__ int lh[512];
    __shared__ int cur[512];
    int t = threadIdx.x;
    if (t < 512) lh[t] = 0;
    __syncthreads();
    int b = blockIdx.x;
    int beg = bbase[b], end = bbase[b + 1];
    for (int i = beg + t; i < end; i += 1024)
        atomicAdd(&lh[bedges[i] & 511], 1);
    __syncthreads();
    int c = (t < 512) ? lh[t] : 0;
    // 512-wide Hillis-Steele inclusive scan; all threads hit the barriers
    for (int off = 1; off < 512; off <<= 1) {
        int a = (t < 512 && t >= off) ? lh[t - off] : 0;
        __syncthreads();
        if (t < 512) lh[t] += a;
        __syncthreads();
    }
    if (t < 512) {
        int d = (b << B2SHIFT) + t;
        int excl = beg + lh[t] - c;
        cur[t] = excl;
        if (d < n) {
            row_ptr[d] = excl;
            dinv[d] = rsqrtf((float)c + 1.0f);
        }
    }
    __syncthreads();
    for (int i = beg + t; i < end; i += 1024) {
        unsigned v = bedges[i];
        int p = atomicAdd(&cur[v & 511], 1);  // LDS atomic
        csr_src[p] = (int)(v >> B2SHIFT);
    }
}

// ---- GEMM layer1: xs1[n+1,64] fp16 = half( dinv[row] * (X W1) ); pad row 0 ----
__global__ __launch_bounds__(256) void gemm64(const float* __restrict__ A,
                                              const float* __restrict__ W,
                                              const float* __restrict__ dinv,
                                              __half* __restrict__ outh, int n) {
    constexpr int K = 64, FO = 64, CPT = 16;
    __shared__ float As[64][K + 4];
    __shared__ float Ws[K][FO];

    const int t = threadIdx.x;
    const int r0 = blockIdx.x * 64;

    if (blockIdx.x == 0 && t < FO)  // zero pad row n
        outh[(size_t)n * FO + t] = __float2half(0.f);

    for (int i = t; i < K * FO / 4; i += 256) {
        int k = i / (FO / 4);
        int c4 = (i % (FO / 4)) * 4;
        *(float4*)&Ws[k][c4] = *(const float4*)&W[k * FO + c4];
    }
    for (int i = t; i < 1024; i += 256) {
        int row = i / 16;
        int c4 = (i % 16) * 4;
        int g = r0 + row;
        float4 v = make_float4(0.f, 0.f, 0.f, 0.f);
        if (g < n) v = *(const float4*)&A[(size_t)g * K + c4];
        *(float4*)&As[row][c4] = v;
    }
    __syncthreads();

    const int row = t >> 2;
    const int c0 = (t & 3) * CPT;
    float acc[CPT];
#pragma unroll
    for (int j = 0; j < CPT; ++j) acc[j] = 0.f;
#pragma unroll
    for (int k = 0; k < K; ++k) {
        float xv = As[row][k];
#pragma unroll
        for (int j = 0; j < CPT; ++j) acc[j] = fmaf(xv, Ws[k][c0 + j], acc[j]);
    }

    int g = r0 + row;
    if (g < n) {
        float sc = dinv[g];
#pragma unroll
        for (int j4 = 0; j4 < CPT; j4 += 4) {
            half4 h;
            h.lo = __floats2half2_rn(acc[j4] * sc, acc[j4 + 1] * sc);
            h.hi = __floats2half2_rn(acc[j4 + 2] * sc, acc[j4 + 3] * sc);
            *(half4*)&outh[(size_t)g * FO + c0 + j4] = h;
        }
    }
}

// ---- fused layer-1 aggregate + layer-2 transform ----
// One wave per dst row. Gather-sum xs1 rows (tail-free 8-deep clamped batches,
// scalarized indices). Then: t = relu(dinv*acc + b1); LDS wave-broadcast of
// the 64-feature row; xW2 split-k over half-waves + shfl_xor(32); xs2[d] =
// half(dinv * (t W2)). Writes fp16 xs2 [n+1,32]; block 0 zeroes pad row.
__global__ __launch_bounds__(256) void agg64_fused(const int* __restrict__ row_ptr,
                                                   const int* __restrict__ csr_src,
                                                   const float* __restrict__ dinv,
                                                   const __half* __restrict__ xs1,
                                                   const float* __restrict__ b1,
                                                   const float* __restrict__ W2,
                                                   __half* __restrict__ xs2, int n) {
    __shared__ float Wsh[64][33];   // [k][c], +1 pad
    __shared__ float b1s[64];
    __shared__ float trow[4][64];
    int t = threadIdx.x;
    for (int i = t; i < 64 * 32; i += 256) Wsh[i >> 5][i & 31] = W2[i];
    if (t < 64) b1s[t] = b1[t];
    __syncthreads();

    if (blockIdx.x == 0 && t < 32) xs2[(size_t)n * 32 + t] = __float2half(0.f);

    int d = __builtin_amdgcn_readfirstlane(blockIdx.x * 4 + (t >> 6));
    if (d >= n) return;
    int lane = t & 63;

    int beg = row_ptr[d];        // uniform -> s_load
    int end = row_ptr[d + 1];
    float acc = __half2float(xs1[(size_t)d * 64 + lane]);  // self-loop

    for (int jb = beg; jb < end; jb += 8) {
        int idx[8];
#pragma unroll
        for (int k = 0; k < 8; ++k) {
            int j = jb + k;
            int s = csr_src[min(j, end - 1)];
            idx[k] = __builtin_amdgcn_readfirstlane((j < end) ? s : n);
        }
        float v[8];
#pragma unroll
        for (int k = 0; k < 8; ++k)
            v[k] = __half2float(xs1[(size_t)idx[k] * 64 + lane]);
        acc += ((v[0] + v[1]) + (v[2] + v[3])) + ((v[4] + v[5]) + (v[6] + v[7]));
    }

    float di = dinv[d];
    float tv = fmaxf(fmaf(di, acc, b1s[lane]), 0.f);  // relu(dinv*acc + b1)

    int w = t >> 6;
    trow[w][lane] = tv;          // same-wave LDS broadcast (lockstep + waitcnt)

    float s = 0.f;
    int c = lane & 31;
    int k0 = (lane >> 5) * 32;   // half-wave split-k
#pragma unroll
    for (int k = 0; k < 32; ++k)
        s = fmaf(trow[w][k0 + k], Wsh[k0 + k][c], s);
    s += __shfl_xor(s, 32);      // combine k-halves

    if (lane < 32)
        xs2[(size_t)d * 32 + c] = __float2half(di * s);
}

// ---- layer-2 aggregate: out[d] = dinv[d]*(sum xs2[s] + xs2[d]) + b2 ----
// 2 rows per wave (32 lanes each), tail-free 8-deep clamped batches.
__global__ __launch_bounds__(256) void agg32(const int* __restrict__ row_ptr,
                                             const int* __restrict__ csr_src,
                                             const float* __restrict__ dinv,
                                             const __half* __restrict__ xs2,
                                             const float* __restrict__ bias,
                                             float* __restrict__ out, int n) {
    int d = blockIdx.x * 8 + (threadIdx.x >> 5);
    int f = threadIdx.x & 31;
    if (d >= n) return;

    int beg = row_ptr[d];
    int end = row_ptr[d + 1];
    float acc = __half2float(xs2[(size_t)d * 32 + f]);  // self-loop

    for (int jb = beg; jb < end; jb += 8) {
        int idx[8];
#pragma unroll
        for (int k = 0; k < 8; ++k) {
            int j = jb + k;
            int s = csr_src[min(j, end - 1)];
            idx[k] = (j < end) ? s : n;   // n = zero pad row
        }
        float v[8];
#pragma unroll
        for (int k = 0; k < 8; ++k)
            v[k] = __half2float(xs2[(size_t)idx[k] * 32 + f]);
        acc += ((v[0] + v[1]) + (v[2] + v[3])) + ((v[4] + v[5]) + (v[6] + v[7]));
    }

    out[(size_t)d * 32 + f] = dinv[d] * acc + bias[f];
}

extern "C" void kernel_launch(void* const* d_in, const int* in_sizes, int n_in,
                              void* d_out, int out_size, void* d_ws, size_t ws_size,
                              hipStream_t stream) {
    const float* x  = (const float*)d_in[0];   // [n, 64]
    const int*   ei = (const int*)d_in[1];     // [2, E]
    const float* W1 = (const float*)d_in[2];   // [64, 64]
    const float* b1 = (const float*)d_in[3];   // [64]
    const float* W2 = (const float*)d_in[4];   // [64, 32]
    const float* b2 = (const float*)d_in[5];   // [32]
    float* out = (float*)d_out;                // [n, 32]

    const int n = in_sizes[0] / N_FEAT_IN;     // 100000
    const int E = in_sizes[1] / 2;             // 1600000
    const int* srcI = ei;
    const int* dstI = ei + E;

    const int NB = (n + 511) >> B2SHIFT;       // 196 coarse buckets
    const int NR = (E + CHUNK - 1) / CHUNK;    // 391 chunks

    // workspace layout (256B aligned)
    char* ws = (char*)d_ws;
    size_t off = 0;
    auto alloc = [&](size_t bytes) {
        void* p = ws + off;
        off += (bytes + 255) & ~(size_t)255;
        return p;
    };
    float*    dinv    = (float*)alloc((size_t)n * 4);
    int*      row_ptr = (int*)alloc((size_t)(n + 1) * 4);
    int*      bbase   = (int*)alloc((size_t)(NB + 1) * 4);
    int*      ctot    = (int*)alloc((size_t)256 * 4);
    int*      cbase   = (int*)alloc((size_t)256 * 4);
    int*      H       = (int*)alloc((size_t)NR * 256 * 4);        // ~400KB
    unsigned* bedges  = (unsigned*)alloc((size_t)E * 4);
    int*      csr_src = (int*)alloc((size_t)E * 4);
    __half*   xs1     = (__half*)alloc((size_t)(n + 1) * 64 * 2); // +pad row
    __half*   xs2     = (__half*)alloc((size_t)(n + 1) * 32 * 2); // +pad row

    // 1) atomic-free bucket sort by dst>>9
    passA_hist<<<NR, 1024, 0, stream>>>(dstI, H, E);
    col_scan_a<<<256, 512, 0, stream>>>(H, ctot, NR);
    col_scan_b<<<1, 256, 0, stream>>>(ctot, cbase, bbase, row_ptr, NB, n, E);
    passB_place<<<NR, 1024, 0, stream>>>(srcI, dstI, H, cbase, bedges, E);

    // 2) merged: row_ptr + dinv + CSR scatter
    bucket_csr<<<NB, 1024, 0, stream>>>(bbase, bedges, row_ptr, dinv, csr_src, n);

    // 3) layer 1 GEMM: xs1 = half(dinv .* (X W1))
    gemm64<<<(n + 63) / 64, 256, 0, stream>>>(x, W1, dinv, xs1, n);

    // 4) fused layer-1 aggregate + layer-2 transform -> xs2
    agg64_fused<<<(n + 3) / 4, 256, 0, stream>>>(row_ptr, csr_src, dinv, xs1,
                                                 b1, W2, xs2, n);

    // 5) layer-2 aggregate -> out
    agg32<<<(n + 7) / 8, 256, 0, stream>>>(row_ptr, csr_src, dinv, xs2, b2, out, n);
}

// Round 13
// 202.685 us; speedup vs baseline: 1.3083x; 1.1559x over previous
//
#include <hip/hip_runtime.h>
#include <hip/hip_bf16.h>
#include <hip/hip_fp16.h>

// GCN 2-layer: out = Ahat * relu(Ahat*(X W1)+b1) * W2 + b2
// Round 13: multi-row gather waves — trade instruction count for lines/instr.
//  - agg64: 4 rows/wave, 16 lanes/row, half4 per lane (lane owns features
//    4c..4c+3 -> NO cross-lane reduction). 1 instr = 4 edges; 8-deep clamped
//    batches = 32 edges in flight/wave. E/4 gather instructions (was E).
//    Epilogue: t = relu(dinv*acc+b1) -> fp16 (un-fuses the W2 GEMM; R12's
//    per-wave GEMM cost ~13us).
//  - gemm32h: tiled fp16-A GEMM t*W2 -> xs2 fp16 (+dinv, pad row).
//  - agg32: 8 rows/wave, 8 lanes/row, half4 -> 8 edges/instr, E/8 instrs.
//  - build pipeline + gemm64 unchanged from R12.

#define N_FEAT_IN 64
#define B2SHIFT 9        // 512 dst nodes per coarse bucket
#define CHUNK 4096       // edges per block in pass A/B

struct alignas(8) half4 { __half2 lo, hi; };

// ---- pass A: per-chunk bucket histogram (LDS, no global atomics) ----
__global__ __launch_bounds__(1024) void passA_hist(const int* __restrict__ dst,
                                                   int* __restrict__ H, int E) {
    __shared__ int h[256];
    int t = threadIdx.x;
    if (t < 256) h[t] = 0;
    __syncthreads();
    int base = blockIdx.x * CHUNK;
    int end = min(base + CHUNK, E);
    for (int i = base + t; i < end; i += 1024)
        atomicAdd(&h[dst[i] >> B2SHIFT], 1);
    __syncthreads();
    if (t < 256) H[blockIdx.x * 256 + t] = h[t];
}

// ---- col_scan_a: one block per column; exclusive scan over NR rows ----
__global__ __launch_bounds__(512) void col_scan_a(int* __restrict__ H,
                                                  int* __restrict__ ctot, int NR) {
    __shared__ int s[512];
    int b = blockIdx.x;
    int t = threadIdx.x;
    int v = (t < NR) ? H[t * 256 + b] : 0;
    s[t] = v;
    __syncthreads();
    for (int off = 1; off < 512; off <<= 1) {
        int a = (t >= off) ? s[t - off] : 0;
        __syncthreads();
        s[t] += a;
        __syncthreads();
    }
    if (t < NR) H[t * 256 + b] = s[t] - v;
    if (t == 511) ctot[b] = s[511];
}

// ---- col_scan_b: scan column totals -> per-bucket bases; row_ptr[n]=E ----
__global__ __launch_bounds__(256) void col_scan_b(const int* __restrict__ ctot,
                                                  int* __restrict__ cbase,
                                                  int* __restrict__ bbase,
                                                  int* __restrict__ row_ptr,
                                                  int NB, int n, int E) {
    __shared__ int s[256];
    int t = threadIdx.x;
    int v = ctot[t];
    s[t] = v;
    __syncthreads();
    for (int off = 1; off < 256; off <<= 1) {
        int a = (t >= off) ? s[t - off] : 0;
        __syncthreads();
        s[t] += a;
        __syncthreads();
    }
    int e = s[t] - v;
    cbase[t] = e;
    if (t < NB) bbase[t] = e;
    if (t == 0) { bbase[NB] = E; row_ptr[n] = E; }
}

// ---- pass B: place packed edges into private per-chunk runs ----
__global__ __launch_bounds__(1024) void passB_place(const int* __restrict__ src,
                                                    const int* __restrict__ dst,
                                                    const int* __restrict__ H,
                                                    const int* __restrict__ cbase,
                                                    unsigned* __restrict__ bedges, int E) {
    __shared__ int cur[256];
    int t = threadIdx.x;
    if (t < 256) cur[t] = H[blockIdx.x * 256 + t] + cbase[t];
    __syncthreads();
    int base = blockIdx.x * CHUNK;
    int end = min(base + CHUNK, E);
    for (int i = base + t; i < end; i += 1024) {
        int d = dst[i];
        int p = atomicAdd(&cur[d >> B2SHIFT], 1);  // LDS atomic
        bedges[p] = ((unsigned)src[i] << B2SHIFT) | (unsigned)(d & 511);
    }
}

// ---- merged: per-bucket hist -> local scan -> row_ptr/dinv -> CSR scatter ----
__global__ __launch_bounds__(1024) void bucket_csr(const int* __restrict__ bbase,
                                                   const unsigned* __restrict__ bedges,
                                                   int* __restrict__ row_ptr,
                                                   float* __restrict__ dinv,
                                                   int* __restrict__ csr_src, int n) {
    __shared__ int lh[512];
    __shared__ int cur[512];
    int t = threadIdx.x;
    if (t < 512) lh[t] = 0;
    __syncthreads();
    int b = blockIdx.x;
    int beg = bbase[b], end = bbase[b + 1];
    for (int i = beg + t; i < end; i += 1024)
        atomicAdd(&lh[bedges[i] & 511], 1);
    __syncthreads();
    int c = (t < 512) ? lh[t] : 0;
    for (int off = 1; off < 512; off <<= 1) {
        int a = (t < 512 && t >= off) ? lh[t - off] : 0;
        __syncthreads();
        if (t < 512) lh[t] += a;
        __syncthreads();
    }
    if (t < 512) {
        int d = (b << B2SHIFT) + t;
        int excl = beg + lh[t] - c;
        cur[t] = excl;
        if (d < n) {
            row_ptr[d] = excl;
            dinv[d] = rsqrtf((float)c + 1.0f);
        }
    }
    __syncthreads();
    for (int i = beg + t; i < end; i += 1024) {
        unsigned v = bedges[i];
        int p = atomicAdd(&cur[v & 511], 1);  // LDS atomic
        csr_src[p] = (int)(v >> B2SHIFT);
    }
}

// ---- GEMM layer1: xs1[n+1,64] fp16 = half( dinv[row] * (X W1) ); pad row 0 ----
__global__ __launch_bounds__(256) void gemm64(const float* __restrict__ A,
                                              const float* __restrict__ W,
                                              const float* __restrict__ dinv,
                                              __half* __restrict__ outh, int n) {
    constexpr int K = 64, FO = 64, CPT = 16;
    __shared__ float As[64][K + 4];
    __shared__ float Ws[K][FO];

    const int t = threadIdx.x;
    const int r0 = blockIdx.x * 64;

    if (blockIdx.x == 0 && t < FO)
        outh[(size_t)n * FO + t] = __float2half(0.f);

    for (int i = t; i < K * FO / 4; i += 256) {
        int k = i / (FO / 4);
        int c4 = (i % (FO / 4)) * 4;
        *(float4*)&Ws[k][c4] = *(const float4*)&W[k * FO + c4];
    }
    for (int i = t; i < 1024; i += 256) {
        int row = i / 16;
        int c4 = (i % 16) * 4;
        int g = r0 + row;
        float4 v = make_float4(0.f, 0.f, 0.f, 0.f);
        if (g < n) v = *(const float4*)&A[(size_t)g * K + c4];
        *(float4*)&As[row][c4] = v;
    }
    __syncthreads();

    const int row = t >> 2;
    const int c0 = (t & 3) * CPT;
    float acc[CPT];
#pragma unroll
    for (int j = 0; j < CPT; ++j) acc[j] = 0.f;
#pragma unroll
    for (int k = 0; k < K; ++k) {
        float xv = As[row][k];
#pragma unroll
        for (int j = 0; j < CPT; ++j) acc[j] = fmaf(xv, Ws[k][c0 + j], acc[j]);
    }

    int g = r0 + row;
    if (g < n) {
        float sc = dinv[g];
#pragma unroll
        for (int j4 = 0; j4 < CPT; j4 += 4) {
            half4 h;
            h.lo = __floats2half2_rn(acc[j4] * sc, acc[j4 + 1] * sc);
            h.hi = __floats2half2_rn(acc[j4 + 2] * sc, acc[j4 + 3] * sc);
            *(half4*)&outh[(size_t)g * FO + c0 + j4] = h;
        }
    }
}

// ---- agg64: 4 rows/wave, 16 lanes/row, half4/lane; t = relu(dinv*acc+b1) ----
// Lane owns features 4c..4c+3 of its row -> no cross-lane reduction.
__global__ __launch_bounds__(256) void agg64(const int* __restrict__ row_ptr,
                                             const int* __restrict__ csr_src,
                                             const float* __restrict__ dinv,
                                             const __half* __restrict__ xs1,
                                             const float* __restrict__ b1,
                                             __half* __restrict__ th, int n) {
    int d = blockIdx.x * 16 + (threadIdx.x >> 4);  // 16 rows/block
    if (d >= n) return;
    int c = threadIdx.x & 15;                      // half4 slice

    int beg = row_ptr[d];
    int end = row_ptr[d + 1];

    half4 sv = *(const half4*)&xs1[(size_t)d * 64 + 4 * c];  // self-loop
    float2 slo = __half22float2(sv.lo), shi = __half22float2(sv.hi);
    float a0 = slo.x, a1 = slo.y, a2 = shi.x, a3 = shi.y;

    for (int jb = beg; jb < end; jb += 8) {
        int idx[8];
#pragma unroll
        for (int k = 0; k < 8; ++k) {
            int j = jb + k;
            int s = csr_src[min(j, end - 1)];   // loop entered => end > beg
            idx[k] = (j < end) ? s : n;         // n = zero pad row
        }
        half4 v[8];
#pragma unroll
        for (int k = 0; k < 8; ++k)
            v[k] = *(const half4*)&xs1[(size_t)idx[k] * 64 + 4 * c];
#pragma unroll
        for (int k = 0; k < 8; ++k) {
            float2 lo = __half22float2(v[k].lo), hi = __half22float2(v[k].hi);
            a0 += lo.x; a1 += lo.y; a2 += hi.x; a3 += hi.y;
        }
    }

    float di = dinv[d];
    float4 bv = *(const float4*)&b1[4 * c];
    float t0 = fmaxf(fmaf(di, a0, bv.x), 0.f);
    float t1 = fmaxf(fmaf(di, a1, bv.y), 0.f);
    float t2 = fmaxf(fmaf(di, a2, bv.z), 0.f);
    float t3 = fmaxf(fmaf(di, a3, bv.w), 0.f);
    half4 h;
    h.lo = __floats2half2_rn(t0, t1);
    h.hi = __floats2half2_rn(t2, t3);
    *(half4*)&th[(size_t)d * 64 + 4 * c] = h;
}

// ---- gemm32h: xs2[n+1,32] fp16 = half( dinv[row] * (t[n,64] W2) ); pad row ----
__global__ __launch_bounds__(256) void gemm32h(const __half* __restrict__ Ah,
                                               const float* __restrict__ W,
                                               const float* __restrict__ dinv,
                                               __half* __restrict__ outh, int n) {
    constexpr int K = 64, FO = 32, CPT = 8;
    __shared__ float As[64][K + 4];
    __shared__ float Ws[K][FO];

    const int t = threadIdx.x;
    const int r0 = blockIdx.x * 64;

    if (blockIdx.x == 0 && t < FO)
        outh[(size_t)n * FO + t] = __float2half(0.f);

    for (int i = t; i < K * FO / 4; i += 256) {
        int k = i / (FO / 4);
        int c4 = (i % (FO / 4)) * 4;
        *(float4*)&Ws[k][c4] = *(const float4*)&W[k * FO + c4];
    }
    for (int i = t; i < 1024; i += 256) {
        int row = i / 16;
        int c4 = (i % 16) * 4;
        int g = r0 + row;
        float4 v = make_float4(0.f, 0.f, 0.f, 0.f);
        if (g < n) {
            half4 hv = *(const half4*)&Ah[(size_t)g * K + c4];
            float2 lo = __half22float2(hv.lo), hi = __half22float2(hv.hi);
            v = make_float4(lo.x, lo.y, hi.x, hi.y);
        }
        *(float4*)&As[row][c4] = v;
    }
    __syncthreads();

    const int row = t >> 2;
    const int c0 = (t & 3) * CPT;
    float acc[CPT];
#pragma unroll
    for (int j = 0; j < CPT; ++j) acc[j] = 0.f;
#pragma unroll
    for (int k = 0; k < K; ++k) {
        float xv = As[row][k];
#pragma unroll
        for (int j = 0; j < CPT; ++j) acc[j] = fmaf(xv, Ws[k][c0 + j], acc[j]);
    }

    int g = r0 + row;
    if (g < n) {
        float sc = dinv[g];
#pragma unroll
        for (int j4 = 0; j4 < CPT; j4 += 4) {
            half4 h;
            h.lo = __floats2half2_rn(acc[j4] * sc, acc[j4 + 1] * sc);
            h.hi = __floats2half2_rn(acc[j4 + 2] * sc, acc[j4 + 3] * sc);
            *(half4*)&outh[(size_t)g * FO + c0 + j4] = h;
        }
    }
}

// ---- agg32: 8 rows/wave, 8 lanes/row, half4/lane; out = dinv*acc + b2 ----
__global__ __launch_bounds__(256) void agg32(const int* __restrict__ row_ptr,
                                             const int* __restrict__ csr_src,
                                             const float* __restrict__ dinv,
                                             const __half* __restrict__ xs2,
                                             const float* __restrict__ b2,
                                             float* __restrict__ out, int n) {
    int d = blockIdx.x * 32 + (threadIdx.x >> 3);  // 32 rows/block
    if (d >= n) return;
    int c = threadIdx.x & 7;                       // half4 slice

    int beg = row_ptr[d];
    int end = row_ptr[d + 1];

    half4 sv = *(const half4*)&xs2[(size_t)d * 32 + 4 * c];  // self-loop
    float2 slo = __half22float2(sv.lo), shi = __half22float2(sv.hi);
    float a0 = slo.x, a1 = slo.y, a2 = shi.x, a3 = shi.y;

    for (int jb = beg; jb < end; jb += 8) {
        int idx[8];
#pragma unroll
        for (int k = 0; k < 8; ++k) {
            int j = jb + k;
            int s = csr_src[min(j, end - 1)];
            idx[k] = (j < end) ? s : n;
        }
        half4 v[8];
#pragma unroll
        for (int k = 0; k < 8; ++k)
            v[k] = *(const half4*)&xs2[(size_t)idx[k] * 32 + 4 * c];
#pragma unroll
        for (int k = 0; k < 8; ++k) {
            float2 lo = __half22float2(v[k].lo), hi = __half22float2(v[k].hi);
            a0 += lo.x; a1 += lo.y; a2 += hi.x; a3 += hi.y;
        }
    }

    float di = dinv[d];
    float4 bv = *(const float4*)&b2[4 * c];
    float4 r;
    r.x = fmaf(di, a0, bv.x);
    r.y = fmaf(di, a1, bv.y);
    r.z = fmaf(di, a2, bv.z);
    r.w = fmaf(di, a3, bv.w);
    *(float4*)&out[(size_t)d * 32 + 4 * c] = r;
}

extern "C" void kernel_launch(void* const* d_in, const int* in_sizes, int n_in,
                              void* d_out, int out_size, void* d_ws, size_t ws_size,
                              hipStream_t stream) {
    const float* x  = (const float*)d_in[0];   // [n, 64]
    const int*   ei = (const int*)d_in[1];     // [2, E]
    const float* W1 = (const float*)d_in[2];   // [64, 64]
    const float* b1 = (const float*)d_in[3];   // [64]
    const float* W2 = (const float*)d_in[4];   // [64, 32]
    const float* b2 = (const float*)d_in[5];   // [32]
    float* out = (float*)d_out;                // [n, 32]

    const int n = in_sizes[0] / N_FEAT_IN;     // 100000
    const int E = in_sizes[1] / 2;             // 1600000
    const int* srcI = ei;
    const int* dstI = ei + E;

    const int NB = (n + 511) >> B2SHIFT;       // 196 coarse buckets
    const int NR = (E + CHUNK - 1) / CHUNK;    // 391 chunks

    // workspace layout (256B aligned)
    char* ws = (char*)d_ws;
    size_t off = 0;
    auto alloc = [&](size_t bytes) {
        void* p = ws + off;
        off += (bytes + 255) & ~(size_t)255;
        return p;
    };
    float*    dinv    = (float*)alloc((size_t)n * 4);
    int*      row_ptr = (int*)alloc((size_t)(n + 1) * 4);
    int*      bbase   = (int*)alloc((size_t)(NB + 1) * 4);
    int*      ctot    = (int*)alloc((size_t)256 * 4);
    int*      cbase   = (int*)alloc((size_t)256 * 4);
    int*      H       = (int*)alloc((size_t)NR * 256 * 4);        // ~400KB
    unsigned* bedges  = (unsigned*)alloc((size_t)E * 4);
    int*      csr_src = (int*)alloc((size_t)E * 4);
    __half*   xs1     = (__half*)alloc((size_t)(n + 1) * 64 * 2); // +pad row
    __half*   th      = (__half*)alloc((size_t)n * 64 * 2);       // relu'd t
    __half*   xs2     = (__half*)alloc((size_t)(n + 1) * 32 * 2); // +pad row

    // 1) atomic-free bucket sort by dst>>9
    passA_hist<<<NR, 1024, 0, stream>>>(dstI, H, E);
    col_scan_a<<<256, 512, 0, stream>>>(H, ctot, NR);
    col_scan_b<<<1, 256, 0, stream>>>(ctot, cbase, bbase, row_ptr, NB, n, E);
    passB_place<<<NR, 1024, 0, stream>>>(srcI, dstI, H, cbase, bedges, E);

    // 2) merged: row_ptr + dinv + CSR scatter
    bucket_csr<<<NB, 1024, 0, stream>>>(bbase, bedges, row_ptr, dinv, csr_src, n);

    // 3) layer 1 GEMM: xs1 = half(dinv .* (X W1))
    gemm64<<<(n + 63) / 64, 256, 0, stream>>>(x, W1, dinv, xs1, n);

    // 4) layer-1 aggregate: t = relu(dinv*(gather+self) + b1)
    agg64<<<(n + 15) / 16, 256, 0, stream>>>(row_ptr, csr_src, dinv, xs1, b1, th, n);

    // 5) layer-2 transform: xs2 = half(dinv .* (t W2))
    gemm32h<<<(n + 63) / 64, 256, 0, stream>>>(th, W2, dinv, xs2, n);

    // 6) layer-2 aggregate -> out
    agg32<<<(n + 31) / 32, 256, 0, stream>>>(row_ptr, csr_src, dinv, xs2, b2, out, n);
}